// Round 1
// baseline (5731.682 us; speedup 1.0000x reference)
//
#include <hip/hip_runtime.h>

// NNUE forward: embedding-bag (2x32 gathers of 256-f32 rows) -> clipped relu
// -> 512->32->32->1 MLP. One wave (64 lanes) per batch element; lane i owns
// dims [4i,4i+4) of each 256-dim accumulator.

constexpr int kBatch  = 131072;
constexpr int kHidden = 256;
constexpr int kBag    = 32;

constexpr int kBlocks        = 512;  // 2 blocks/CU (LDS-limited), 256 CUs
constexpr int kTpb           = 256;  // 4 waves
constexpr int kWavesPerBlock = kTpb / 64;
constexpr int kTotalWaves    = kBlocks * kWavesPerBlock;   // 2048
constexpr int kElemsPerWave  = kBatch / kTotalWaves;       // 64
static_assert(kBatch % kTotalWaves == 0, "batch must divide evenly");

__device__ __forceinline__ float clip1(float x) {
  return fminf(fmaxf(x, 0.0f), 1.0f);  // v_med3_f32
}

// Butterfly reduce-scatter: input p[32] per lane (partial for every output j);
// output: full sum over 64 lanes of p[j], delivered to lanes 2j and 2j+1.
// Stage with xor-distance d consumes lane bit log2(d) as output-index bit:
// final j = (lane >> 1). ~4 VALU ops per surviving value per stage.
__device__ __forceinline__ float reduce_scatter32(float* p, int lane) {
#pragma unroll
  for (int s = 0; s < 5; ++s) {
    const int d    = 32 >> s;  // 32,16,8,4,2
    const int half = 16 >> s;  // 16,8,4,2,1
    const bool up  = (lane & d) != 0;
#pragma unroll
    for (int i = 0; i < half; ++i) {
      const float send = up ? p[i] : p[i + half];
      const float recv = __shfl_xor(send, d, 64);
      p[i] = (up ? p[i + half] : p[i]) + recv;
    }
  }
  // p[0] now summed over the 32 lanes matching bit0; fold the last bit.
  return p[0] + __shfl_xor(p[0], 1, 64);
}

__global__ __launch_bounds__(kTpb, 2) void nnue_fwd(
    const int* __restrict__ idx_us, const int* __restrict__ idx_th,
    const float* __restrict__ emb, const float* __restrict__ w1,
    const float* __restrict__ b1, const float* __restrict__ w2,
    const float* __restrict__ b2, const float* __restrict__ wo,
    const float* __restrict__ bo, float* __restrict__ out) {
  __shared__ float sW1[32][512];    // 64 KB, read as [j][4*lane] float4 (conflict-free)
  __shared__ float sW2T[32][36];    // transposed + pad 4: row stride 36 -> 4-way max
  __shared__ float sB1[32], sB2[32], sWo[32];

  const int t = threadIdx.x;
  {  // stage W1: 16384 floats = 4096 float4, 16 per thread
    const float4* src = (const float4*)w1;
    float4* dst = (float4*)&sW1[0][0];
#pragma unroll
    for (int i = 0; i < 16; ++i) dst[i * kTpb + t] = src[i * kTpb + t];
  }
  for (int i = t; i < 32 * 32; i += kTpb) {
    sW2T[i & 31][i >> 5] = w2[i];  // w2[j2][j] -> sW2T[j][j2]
  }
  if (t < 32) { sB1[t] = b1[t]; sB2[t] = b2[t]; sWo[t] = wo[t]; }
  __syncthreads();

  const float outb = bo[0];
  const int lane = t & 63;
  const int wid  = blockIdx.x * kWavesPerBlock + (t >> 6);
  const int myj  = lane >> 1;

  for (int e = 0; e < kElemsPerWave; ++e) {
    const int b = wid * kElemsPerWave + e;

    // lanes 0..31 load us-indices, lanes 32..63 load them-indices (coalesced)
    const int* ip = (lane < kBag) ? (idx_us + (size_t)b * kBag + lane)
                                  : (idx_th + (size_t)b * kBag + (lane - kBag));
    const int vidx = *ip;

    // ---- embedding-bag gather: wave reads one full 1KB row per index ----
    float4 au = make_float4(0.f, 0.f, 0.f, 0.f);
    float4 at = make_float4(0.f, 0.f, 0.f, 0.f);
#pragma unroll
    for (int i = 0; i < kBag; ++i) {
      const int iu = __builtin_amdgcn_readlane(vidx, i);  // SGPR row base
      const float4 v = ((const float4*)(emb + (size_t)iu * kHidden))[lane];
      au.x += v.x; au.y += v.y; au.z += v.z; au.w += v.w;
    }
#pragma unroll
    for (int i = 0; i < kBag; ++i) {
      const int it2 = __builtin_amdgcn_readlane(vidx, i + kBag);
      const float4 v = ((const float4*)(emb + (size_t)it2 * kHidden))[lane];
      at.x += v.x; at.y += v.y; at.z += v.z; at.w += v.w;
    }

    au.x = clip1(au.x); au.y = clip1(au.y); au.z = clip1(au.z); au.w = clip1(au.w);
    at.x = clip1(at.x); at.y = clip1(at.y); at.z = clip1(at.z); at.w = clip1(at.w);

    // ---- layer 1: per-lane partials over this lane's 8 x-values ----
    float p[32];
#pragma unroll 8
    for (int j = 0; j < 32; ++j) {
      const float4 a = *(const float4*)&sW1[j][4 * lane];
      const float4 c = *(const float4*)&sW1[j][kHidden + 4 * lane];
      p[j] = au.x * a.x + au.y * a.y + au.z * a.z + au.w * a.w +
             at.x * c.x + at.y * c.y + at.z * c.z + at.w * c.w;
    }
    // y1 for output (lane>>1); *0.5 pre-compensates the 2x lane duplication
    // in the next reduction (lanes 2j and 2j+1 hold the same y1).
    const float y1 = clip1(reduce_scatter32(p, lane) + sB1[myj]) * 0.5f;

    // ---- layer 2: lane holds x2 = y1c[myj]; partial for every j2 ----
    float q[32];
    const float4* wrow = (const float4*)&sW2T[myj][0];
#pragma unroll
    for (int j8 = 0; j8 < 8; ++j8) {
      const float4 wv = wrow[j8];
      q[4 * j8 + 0] = y1 * wv.x;
      q[4 * j8 + 1] = y1 * wv.y;
      q[4 * j8 + 2] = y1 * wv.z;
      q[4 * j8 + 3] = y1 * wv.w;
    }
    const float y2 = clip1(reduce_scatter32(q, lane) + sB2[myj]) * 0.5f;

    // ---- output layer: dot(y2c, wo) over 32 outputs (x2 lane dup -> 0.5) ----
    float p3 = y2 * sWo[myj];
#pragma unroll
    for (int d = 1; d < 64; d <<= 1) p3 += __shfl_xor(p3, d, 64);
    if (lane == 0) out[b] = p3 + outb;
  }
}

extern "C" void kernel_launch(void* const* d_in, const int* in_sizes, int n_in,
                              void* d_out, int out_size, void* d_ws, size_t ws_size,
                              hipStream_t stream) {
  const int* idx_us  = (const int*)d_in[0];
  const int* idx_th  = (const int*)d_in[1];
  const float* emb   = (const float*)d_in[2];
  const float* w1    = (const float*)d_in[3];
  const float* b1    = (const float*)d_in[4];
  const float* w2    = (const float*)d_in[5];
  const float* b2    = (const float*)d_in[6];
  const float* wo    = (const float*)d_in[7];
  const float* bo    = (const float*)d_in[8];
  float* out         = (float*)d_out;

  nnue_fwd<<<kBlocks, kTpb, 0, stream>>>(idx_us, idx_th, emb, w1, b1, w2, b2,
                                         wo, bo, out);
}

// Round 2
// 1088.528 us; speedup vs baseline: 5.2655x; 5.2655x over previous
//
#include <hip/hip_runtime.h>

// NNUE forward: embedding-bag (2x32 gathers of 256-f32 rows) -> clipped relu
// -> 512->32->32->1 MLP. One wave (64 lanes) per batch element; lane i owns
// dims [4i,4i+4) of each 256-dim accumulator.
//
// R2: scratch-spill fix. The R1 kernel's reduce_scatter took float* and had a
// variable inner-loop bound -> alloca -> 1.79 GB of scratch traffic on the
// butterfly's critical path. Now: compile-time-unrolled butterfly stages
// (template<int D,int HALF>), layer-2/3 via per-wave LDS broadcast + W2 rows
// held in persistent VGPRs (no q[32], no second butterfly).

constexpr int kBatch  = 131072;
constexpr int kHidden = 256;
constexpr int kBag    = 32;

constexpr int kBlocks        = 512;  // 2 blocks/CU (LDS-limited), 256 CUs
constexpr int kTpb           = 256;  // 4 waves
constexpr int kWavesPerBlock = kTpb / 64;
constexpr int kTotalWaves    = kBlocks * kWavesPerBlock;   // 2048
constexpr int kElemsPerWave  = kBatch / kTotalWaves;       // 64
static_assert(kBatch % kTotalWaves == 0, "batch must divide evenly");

__device__ __forceinline__ float clip1(float x) {
  return fminf(fmaxf(x, 0.0f), 1.0f);  // v_med3_f32
}

// One butterfly reduce-scatter stage; ALL indices compile-time constants so
// p[] stays in VGPRs (rule #20: no runtime indexing).
template <int D, int HALF>
__device__ __forceinline__ void rs_stage(float (&p)[32], int lane) {
  const bool up = (lane & D) != 0;
#pragma unroll
  for (int i = 0; i < HALF; ++i) {
    const float send = up ? p[i] : p[i + HALF];
    const float recv = __shfl_xor(send, D, 64);
    p[i] = (up ? p[i + HALF] : p[i]) + recv;
  }
}

// Full 64-lane reduce of 32 per-lane partials; result (sum over all lanes of
// p[j]) delivered to lanes 2j and 2j+1 (j = lane>>1).
__device__ __forceinline__ float reduce32(float (&p)[32], int lane) {
  rs_stage<32, 16>(p, lane);
  rs_stage<16, 8>(p, lane);
  rs_stage<8, 4>(p, lane);
  rs_stage<4, 2>(p, lane);
  rs_stage<2, 1>(p, lane);
  return p[0] + __shfl_xor(p[0], 1, 64);
}

__global__ __launch_bounds__(kTpb, 2) void nnue_fwd(
    const int* __restrict__ idx_us, const int* __restrict__ idx_th,
    const float* __restrict__ emb, const float* __restrict__ w1,
    const float* __restrict__ b1, const float* __restrict__ w2,
    const float* __restrict__ b2, const float* __restrict__ wo,
    const float* __restrict__ bo, float* __restrict__ out) {
  __shared__ float sW1[32][512];  // 64 KB, read as [j][4*lane] float4
  __shared__ __align__(16) float sY1[kWavesPerBlock][32];  // per-wave y1

  const int t = threadIdx.x;
  {  // stage W1: 16384 floats = 4096 float4, 16 per thread
    const float4* src = (const float4*)w1;
    float4* dst = (float4*)&sW1[0][0];
#pragma unroll
    for (int i = 0; i < 16; ++i) dst[i * kTpb + t] = src[i * kTpb + t];
  }
  __syncthreads();

  const int lane   = t & 63;
  const int wlocal = t >> 6;
  const int wid    = blockIdx.x * kWavesPerBlock + wlocal;
  const int myj    = lane >> 1;  // layer-1 output this lane ends up holding
  const int j2     = lane & 31;  // layer-2/3 row this lane owns

  // Small weights pinned in registers (one-time, tiny tables -> L1).
  const float b1r  = b1[myj];
  const float b2r  = b2[j2];
  const float wor  = wo[j2];
  const float outb = bo[0];
  float w2r[32];  // lane's W2 row; only constant-indexed below
#pragma unroll
  for (int k = 0; k < 32; ++k) w2r[k] = w2[j2 * 32 + k];

  for (int e = 0; e < kElemsPerWave; ++e) {
    const int b = wid * kElemsPerWave + e;

    // lanes 0..31 load us-indices, lanes 32..63 load them-indices (coalesced)
    const int* ip = (lane < kBag) ? (idx_us + (size_t)b * kBag + lane)
                                  : (idx_th + (size_t)b * kBag + (lane - kBag));
    const int vidx = *ip;

    // ---- embedding-bag gather: wave reads one full 1KB row per index ----
    float4 au = make_float4(0.f, 0.f, 0.f, 0.f);
    float4 at = make_float4(0.f, 0.f, 0.f, 0.f);
#pragma unroll
    for (int i = 0; i < kBag; ++i) {
      const int iu = __builtin_amdgcn_readlane(vidx, i);  // SGPR row base
      const float4 v = ((const float4*)(emb + (size_t)iu * kHidden))[lane];
      au.x += v.x; au.y += v.y; au.z += v.z; au.w += v.w;
    }
#pragma unroll
    for (int i = 0; i < kBag; ++i) {
      const int it2 = __builtin_amdgcn_readlane(vidx, i + kBag);
      const float4 v = ((const float4*)(emb + (size_t)it2 * kHidden))[lane];
      at.x += v.x; at.y += v.y; at.z += v.z; at.w += v.w;
    }

    au.x = clip1(au.x); au.y = clip1(au.y); au.z = clip1(au.z); au.w = clip1(au.w);
    at.x = clip1(at.x); at.y = clip1(at.y); at.z = clip1(at.z); at.w = clip1(at.w);

    // ---- layer 1: per-lane partials over this lane's 8 x-values ----
    float p[32];
#pragma unroll
    for (int j = 0; j < 32; ++j) {
      const float4 a = *(const float4*)&sW1[j][4 * lane];
      const float4 c = *(const float4*)&sW1[j][kHidden + 4 * lane];
      p[j] = au.x * a.x + au.y * a.y + au.z * a.z + au.w * a.w +
             at.x * c.x + at.y * c.y + at.z * c.z + at.w * c.w;
    }
    const float y1 = clip1(reduce32(p, lane) + b1r);  // lanes 2j,2j+1 hold y1[j]

    // publish y1[0..31] to the wave via per-wave LDS (no barrier: same wave)
    if ((lane & 1) == 0) sY1[wlocal][myj] = y1;
    asm volatile("s_waitcnt lgkmcnt(0)" ::: "memory");

    // ---- layer 2: lane computes y2[j2] = dot(w2[j2][:], y1[:]) ----
    const float4* y4 = (const float4*)&sY1[wlocal][0];  // broadcast reads
    float y2 = b2r;
#pragma unroll
    for (int k4 = 0; k4 < 8; ++k4) {
      const float4 y = y4[k4];
      y2 += w2r[4 * k4 + 0] * y.x + w2r[4 * k4 + 1] * y.y +
            w2r[4 * k4 + 2] * y.z + w2r[4 * k4 + 3] * y.w;
    }
    y2 = clip1(y2);

    // ---- output layer: sum_j2 wo[j2]*y2[j2] within each 32-lane half ----
    float acc = y2 * wor;
#pragma unroll
    for (int d = 1; d < 32; d <<= 1) acc += __shfl_xor(acc, d, 64);
    if (lane == 0) out[b] = acc + outb;
  }
}

extern "C" void kernel_launch(void* const* d_in, const int* in_sizes, int n_in,
                              void* d_out, int out_size, void* d_ws, size_t ws_size,
                              hipStream_t stream) {
  const int* idx_us  = (const int*)d_in[0];
  const int* idx_th  = (const int*)d_in[1];
  const float* emb   = (const float*)d_in[2];
  const float* w1    = (const float*)d_in[3];
  const float* b1    = (const float*)d_in[4];
  const float* w2    = (const float*)d_in[5];
  const float* b2    = (const float*)d_in[6];
  const float* wo    = (const float*)d_in[7];
  const float* bo    = (const float*)d_in[8];
  float* out         = (float*)d_out;

  nnue_fwd<<<kBlocks, kTpb, 0, stream>>>(idx_us, idx_th, emb, w1, b1, w2, b2,
                                         wo, bo, out);
}

// Round 3
// 498.130 us; speedup vs baseline: 11.5064x; 2.1852x over previous
//
#include <hip/hip_runtime.h>
#include <hip/hip_fp16.h>

// NNUE forward: embedding-bag (2x32 gathers of 256-dim rows) -> clipped relu
// -> 512->32->32->1 MLP. One wave per batch element.
//
// R3: gather-byte reduction. R2 counters: VALUBusy 15%, occupancy 22%
// (LDS-limited), 4.06 GB/dispatch L2-miss traffic at 3.7 TB/s -> bound by
// gather volume through L2/L3. Changes:
//  - embedding table converted to f16 in d_ws once per launch (halves gather
//    bytes; 21 MB table is far more L2-resident than 42 MB)
//  - half-wave-per-row gather: lanes 0-31 read row idx[2s], lanes 32-63 read
//    row idx[2s+1], 16B/lane -> one coalesced 1KB load per 2 rows
//  - W1 staged as f16 in LDS (32 KB) -> 4 blocks/CU (16 waves/CU, 2x occ.)
//  - fallback to the f32 R2 kernel if ws_size < f16 table size

constexpr int kBatch  = 131072;
constexpr int kHidden = 256;
constexpr int kBag    = 32;
constexpr int kFeat   = 40960;

__device__ __forceinline__ float clip1(float x) {
  return fminf(fmaxf(x, 0.0f), 1.0f);  // v_med3_f32
}

// One butterfly reduce-scatter stage; ALL indices compile-time constants so
// p[] stays in VGPRs (rule #20: no runtime indexing).
template <int D, int HALF>
__device__ __forceinline__ void rs_stage(float (&p)[32], int lane) {
  const bool up = (lane & D) != 0;
#pragma unroll
  for (int i = 0; i < HALF; ++i) {
    const float send = up ? p[i] : p[i + HALF];
    const float recv = __shfl_xor(send, D, 64);
    p[i] = (up ? p[i + HALF] : p[i]) + recv;
  }
}

// Full 64-lane reduce of 32 per-lane partials; sum of p[j] over all lanes
// delivered to lanes 2j and 2j+1 (j = lane>>1).
__device__ __forceinline__ float reduce32(float (&p)[32], int lane) {
  rs_stage<32, 16>(p, lane);
  rs_stage<16, 8>(p, lane);
  rs_stage<8, 4>(p, lane);
  rs_stage<4, 2>(p, lane);
  rs_stage<2, 1>(p, lane);
  return p[0] + __shfl_xor(p[0], 1, 64);
}

// ---------------------------------------------------------------------------
// emb f32 -> f16 (RNE) convert, 8B coalesced stores
__global__ void cvt_emb(const float4* __restrict__ src, uint2* __restrict__ dst) {
  const int n4 = kFeat * kHidden / 4;  // 2,621,440 float4s
  const int stride = gridDim.x * blockDim.x;
  for (int i = blockIdx.x * blockDim.x + threadIdx.x; i < n4; i += stride) {
    const float4 v = src[i];
    union { __half2 h[2]; uint2 u; } P;
    P.h[0] = __floats2half2_rn(v.x, v.y);
    P.h[1] = __floats2half2_rn(v.z, v.w);
    dst[i] = P.u;
  }
}

// ---------------------------------------------------------------------------
// f16 fast path
constexpr int kBlocksH = 1024;  // 4 blocks/CU resident (33 KB LDS each)
constexpr int kTpb     = 256;   // 4 waves
constexpr int kWpb     = kTpb / 64;
constexpr int kElemsH  = kBatch / (kBlocksH * kWpb);  // 32
static_assert(kBatch % (kBlocksH * kWpb) == 0);

__device__ __forceinline__ void acc8(float (&a)[8], const uint4 v) {
  union { uint4 u; __half2 h[4]; } U;
  U.u = v;
#pragma unroll
  for (int q = 0; q < 4; ++q) {
    const float2 f = __half22float2(U.h[q]);
    a[2 * q + 0] += f.x;
    a[2 * q + 1] += f.y;
  }
}

__global__ __launch_bounds__(kTpb, 4) void nnue_fwd_h(
    const int* __restrict__ idx_us, const int* __restrict__ idx_th,
    const __half* __restrict__ embh, const float* __restrict__ w1,
    const float* __restrict__ b1, const float* __restrict__ w2,
    const float* __restrict__ b2, const float* __restrict__ wo,
    const float* __restrict__ bo, float* __restrict__ out) {
  // sW1h linear layout == row-major f16 W1: entry (j, L, k) = w1[j][8L+k].
  __shared__ __align__(16) __half sW1h[32 * 512];  // 32 KB
  __shared__ __align__(16) float sY1[kWpb][32];    // per-wave y1 broadcast

  const int t = threadIdx.x;
  {  // stage W1 as f16: thread t converts floats [64t, 64t+64)
    const float4* src = (const float4*)w1;
#pragma unroll
    for (int c = 0; c < 16; ++c) {
      const float4 v = src[t * 16 + c];
      __half2* d = (__half2*)&sW1h[t * 64 + 4 * c];
      d[0] = __floats2half2_rn(v.x, v.y);
      d[1] = __floats2half2_rn(v.z, v.w);
    }
  }
  __syncthreads();

  const int lane   = t & 63;
  const int wlocal = t >> 6;
  const int wid    = blockIdx.x * kWpb + wlocal;
  const int myj    = lane >> 1;  // layer-1 output this lane ends up holding
  const int j2     = lane & 31;  // layer-2/3 row this lane owns
  const int half31 = lane & 31;
  const bool hiHalf = lane >= 32;

  // Small weights pinned in registers.
  const float b1r  = b1[myj];
  const float b2r  = b2[j2];
  const float wor  = wo[j2];
  const float outb = bo[0];
  float w2r[32];  // lane's W2 row; only constant-indexed below
#pragma unroll
  for (int k = 0; k < 32; ++k) w2r[k] = w2[j2 * 32 + k];

  for (int e = 0; e < kElemsH; ++e) {
    const int b = wid * kElemsH + e;

    // lanes 0..31 hold us-indices, lanes 32..63 hold them-indices
    const int* ip = (lane < kBag) ? (idx_us + (size_t)b * kBag + lane)
                                  : (idx_th + (size_t)b * kBag + (lane - kBag));
    const int vidx = *ip;

    // ---- gather: each 1KB load covers TWO f16 rows (half-wave each) ----
    float aU[8] = {0, 0, 0, 0, 0, 0, 0, 0};
    float aT[8] = {0, 0, 0, 0, 0, 0, 0, 0};
#pragma unroll
    for (int s = 0; s < 16; ++s) {
      const int rA = __builtin_amdgcn_readlane(vidx, 2 * s);
      const int rB = __builtin_amdgcn_readlane(vidx, 2 * s + 1);
      const int row = hiHalf ? rB : rA;
      const uint4 v = ((const uint4*)embh)[row * 32 + half31];
      acc8(aU, v);
    }
#pragma unroll
    for (int s = 0; s < 16; ++s) {
      const int rA = __builtin_amdgcn_readlane(vidx, 32 + 2 * s);
      const int rB = __builtin_amdgcn_readlane(vidx, 33 + 2 * s);
      const int row = hiHalf ? rB : rA;
      const uint4 v = ((const uint4*)embh)[row * 32 + half31];
      acc8(aT, v);
    }
    // fold the two half-wave partial sums: every lane ends with full sums of
    // us-dims[8*(lane&31)..+8) in aU and them-dims[...] in aT
#pragma unroll
    for (int k = 0; k < 8; ++k) {
      aU[k] += __shfl_xor(aU[k], 32, 64);
      aT[k] += __shfl_xor(aT[k], 32, 64);
    }

    // lane's 8 concat-x values: lanes 0-31 own cols [8L..), lanes 32-63 own
    // cols [256+8(L-32)..) = [8L..) -- exactly w1 cols 8*lane.
    float x8[8];
#pragma unroll
    for (int k = 0; k < 8; ++k) x8[k] = clip1(hiHalf ? aT[k] : aU[k]);

    // ---- layer 1: p[j] = sum over this lane's 8 cols of w1[j][8*lane+k]*x
    float p[32];
#pragma unroll
    for (int j = 0; j < 32; ++j) {
      const uint4 wv = *(const uint4*)&sW1h[(j * 64 + lane) * 8];
      union { uint4 u; __half2 h[4]; } W;
      W.u = wv;
      float s = 0.f;
#pragma unroll
      for (int q = 0; q < 4; ++q) {
        const float2 f = __half22float2(W.h[q]);
        s += f.x * x8[2 * q] + f.y * x8[2 * q + 1];
      }
      p[j] = s;
    }
    const float y1 = clip1(reduce32(p, lane) + b1r);  // lanes 2j,2j+1 hold y1[j]

    // publish y1[0..31] to the wave via per-wave LDS (no barrier: same wave)
    if ((lane & 1) == 0) sY1[wlocal][myj] = y1;
    asm volatile("s_waitcnt lgkmcnt(0)" ::: "memory");

    // ---- layer 2: lane computes y2[j2] = dot(w2[j2][:], y1[:]) ----
    const float4* y4 = (const float4*)&sY1[wlocal][0];  // broadcast reads
    float y2 = b2r;
#pragma unroll
    for (int k4 = 0; k4 < 8; ++k4) {
      const float4 y = y4[k4];
      y2 += w2r[4 * k4 + 0] * y.x + w2r[4 * k4 + 1] * y.y +
            w2r[4 * k4 + 2] * y.z + w2r[4 * k4 + 3] * y.w;
    }
    y2 = clip1(y2);

    // ---- output layer: sum over j2 within each 32-lane half ----
    float acc = y2 * wor;
#pragma unroll
    for (int d = 1; d < 32; d <<= 1) acc += __shfl_xor(acc, d, 64);
    if (lane == 0) out[b] = acc + outb;
  }
}

// ---------------------------------------------------------------------------
// f32 fallback (the R2 kernel) in case ws_size can't hold the f16 table
constexpr int kBlocksF = 512;
constexpr int kElemsF  = kBatch / (kBlocksF * kWpb);  // 64

__global__ __launch_bounds__(kTpb, 2) void nnue_fwd_f32(
    const int* __restrict__ idx_us, const int* __restrict__ idx_th,
    const float* __restrict__ emb, const float* __restrict__ w1,
    const float* __restrict__ b1, const float* __restrict__ w2,
    const float* __restrict__ b2, const float* __restrict__ wo,
    const float* __restrict__ bo, float* __restrict__ out) {
  __shared__ float sW1[32][512];
  __shared__ __align__(16) float sY1[kWpb][32];

  const int t = threadIdx.x;
  {
    const float4* src = (const float4*)w1;
    float4* dst = (float4*)&sW1[0][0];
#pragma unroll
    for (int i = 0; i < 16; ++i) dst[i * kTpb + t] = src[i * kTpb + t];
  }
  __syncthreads();

  const int lane   = t & 63;
  const int wlocal = t >> 6;
  const int wid    = blockIdx.x * kWpb + wlocal;
  const int myj    = lane >> 1;
  const int j2     = lane & 31;

  const float b1r  = b1[myj];
  const float b2r  = b2[j2];
  const float wor  = wo[j2];
  const float outb = bo[0];
  float w2r[32];
#pragma unroll
  for (int k = 0; k < 32; ++k) w2r[k] = w2[j2 * 32 + k];

  for (int e = 0; e < kElemsF; ++e) {
    const int b = wid * kElemsF + e;
    const int* ip = (lane < kBag) ? (idx_us + (size_t)b * kBag + lane)
                                  : (idx_th + (size_t)b * kBag + (lane - kBag));
    const int vidx = *ip;

    float4 au = make_float4(0.f, 0.f, 0.f, 0.f);
    float4 at = make_float4(0.f, 0.f, 0.f, 0.f);
#pragma unroll
    for (int i = 0; i < kBag; ++i) {
      const int iu = __builtin_amdgcn_readlane(vidx, i);
      const float4 v = ((const float4*)(emb + (size_t)iu * kHidden))[lane];
      au.x += v.x; au.y += v.y; au.z += v.z; au.w += v.w;
    }
#pragma unroll
    for (int i = 0; i < kBag; ++i) {
      const int it2 = __builtin_amdgcn_readlane(vidx, i + kBag);
      const float4 v = ((const float4*)(emb + (size_t)it2 * kHidden))[lane];
      at.x += v.x; at.y += v.y; at.z += v.z; at.w += v.w;
    }

    au.x = clip1(au.x); au.y = clip1(au.y); au.z = clip1(au.z); au.w = clip1(au.w);
    at.x = clip1(at.x); at.y = clip1(at.y); at.z = clip1(at.z); at.w = clip1(at.w);

    float p[32];
#pragma unroll
    for (int j = 0; j < 32; ++j) {
      const float4 a = *(const float4*)&sW1[j][4 * lane];
      const float4 c = *(const float4*)&sW1[j][kHidden + 4 * lane];
      p[j] = au.x * a.x + au.y * a.y + au.z * a.z + au.w * a.w +
             at.x * c.x + at.y * c.y + at.z * c.z + at.w * c.w;
    }
    const float y1 = clip1(reduce32(p, lane) + b1r);

    if ((lane & 1) == 0) sY1[wlocal][myj] = y1;
    asm volatile("s_waitcnt lgkmcnt(0)" ::: "memory");

    const float4* y4 = (const float4*)&sY1[wlocal][0];
    float y2 = b2r;
#pragma unroll
    for (int k4 = 0; k4 < 8; ++k4) {
      const float4 y = y4[k4];
      y2 += w2r[4 * k4 + 0] * y.x + w2r[4 * k4 + 1] * y.y +
            w2r[4 * k4 + 2] * y.z + w2r[4 * k4 + 3] * y.w;
    }
    y2 = clip1(y2);

    float acc = y2 * wor;
#pragma unroll
    for (int d = 1; d < 32; d <<= 1) acc += __shfl_xor(acc, d, 64);
    if (lane == 0) out[b] = acc + outb;
  }
}

extern "C" void kernel_launch(void* const* d_in, const int* in_sizes, int n_in,
                              void* d_out, int out_size, void* d_ws, size_t ws_size,
                              hipStream_t stream) {
  const int* idx_us  = (const int*)d_in[0];
  const int* idx_th  = (const int*)d_in[1];
  const float* emb   = (const float*)d_in[2];
  const float* w1    = (const float*)d_in[3];
  const float* b1    = (const float*)d_in[4];
  const float* w2    = (const float*)d_in[5];
  const float* b2    = (const float*)d_in[6];
  const float* wo    = (const float*)d_in[7];
  const float* bo    = (const float*)d_in[8];
  float* out         = (float*)d_out;

  const size_t embh_bytes = (size_t)kFeat * kHidden * sizeof(__half);  // 21 MB
  if (ws_size >= embh_bytes) {
    __half* embh = (__half*)d_ws;
    cvt_emb<<<2048, 256, 0, stream>>>((const float4*)emb, (uint2*)embh);
    nnue_fwd_h<<<kBlocksH, kTpb, 0, stream>>>(idx_us, idx_th, embh, w1, b1, w2,
                                              b2, wo, bo, out);
  } else {
    nnue_fwd_f32<<<kBlocksF, kTpb, 0, stream>>>(idx_us, idx_th, emb, w1, b1,
                                                w2, b2, wo, bo, out);
  }
}